// Round 2
// baseline (154.405 us; speedup 1.0000x reference)
//
#include <hip/hip_runtime.h>
#include <math.h>

namespace {
constexpr int B = 4, P = 64, V = 32, D = 256;
constexpr float MARGIN = 0.1f;
constexpr float L_REG = 0.1f, L_SIGMA = 0.05f;

constexpr int NPAIRW = B * P * (P / 2);   // 8192 pair-waves (2 p's per wave)
constexpr int NCOSTB = NPAIRW / 4;        // 2048 cost blocks (4 waves each)
constexpr int NBLOCKS = NCOSTB + B;       // + 4 reg/sig blocks

// d_ws layout
constexpr size_t WS_COSTS = 0;            // B*P*P floats = 64 KiB
constexpr size_t WS_REG   = 65536;        // 4 floats (raw sums)
constexpr size_t WS_SIG   = WS_REG + 16;  // 4 floats (raw sums)
constexpr size_t WS_CTR   = 65600;        // 1 uint, zeroed via hipMemsetAsync

__global__ __launch_bounds__(256) void fused_kernel(
    const float* __restrict__ gt,    // (B,P,V,2)
    const float* __restrict__ pred,  // (B,P,V,2)
    const float* __restrict__ mu,    // (B,P,D)
    const float* __restrict__ sigma, // (B,P,D)
    const int*   __restrict__ mask,  // (B,P,V)
    const int*   __restrict__ cls,   // (B,P)
    float*       __restrict__ out,   // 5*B
    char*        __restrict__ ws)
{
    float*    costs  = (float*)(ws + WS_COSTS);
    float*    regsum = (float*)(ws + WS_REG);
    float*    sigsum = (float*)(ws + WS_SIG);
    unsigned* ctr    = (unsigned*)(ws + WS_CTR);
    const int t = threadIdx.x;

    // shared: epilogue tile + reduction scratch
    __shared__ float sc[P * P];           // 16 KiB, one batch's costs
    __shared__ float diag[P];
    __shared__ float rowmax[P], colmax[P];
    __shared__ float wred[8];             // wreg[4] | wsig[4]
    __shared__ int   iflag;               // broken flag / isLast flag

    if (blockIdx.x < NCOSTB) {
        // ---- cost blocks: one wave handles (b, g, p0..p1); lane = 32*half + r
        const int wid  = blockIdx.x * 4 + (t >> 6);   // pair-wave id [0, 8192)
        const int lane = t & 63;
        const int half = lane >> 5;
        const int r    = lane & 31;
        const int b    = wid >> 11;                   // / (P * P/2)
        const int rem  = wid & 2047;
        const int g    = rem >> 5;
        const int p    = ((rem & 31) << 1) | half;

        const int mg = mask[(b * P + g) * V + r];
        const int mp = mask[(b * P + p) * V + r];
        const unsigned long long bg = __ballot(mg == 0);
        const unsigned long long bp = __ballot(mp == 0);
        const int nvg = __popcll(bg & 0xffffffffULL);           // same both halves
        const int nvp = half ? __popcll(bp >> 32) : __popcll(bp & 0xffffffffULL);
        const int mn  = (nvg < nvp) ? nvg : nvp;
        const bool is_poly = (cls[b * P + g] == 1);

        const float* gtg = gt   + (size_t)(b * P + g) * (V * 2);
        const float* prp = pred + (size_t)(b * P + p) * (V * 2);

        const bool valid = is_poly ? (r < nvg) : (r < 2);
        int wrapm, idx, step;
        if (is_poly) { wrapm = (nvg > 0) ? nvg : 1; idx = (r < nvg) ? r : 0; step = 1; }
        else         { wrapm = V; idx = (r == 1) ? (V - 1) : 0; step = (r == 1) ? -1 : 1; }

        const int mn_other = __shfl_xor(mn, 32);
        const int loopN = (mn > mn_other) ? mn : mn_other;

        float s = 0.0f;
        for (int v = 0; v < loopN; ++v) {
            if (v < mn) {
                const float gx = gtg[2 * idx], gy = gtg[2 * idx + 1];
                const float px = prp[2 * v],   py = prp[2 * v + 1];
                s += fabsf(gx - px) + fabsf(gy - py);
            }
            idx += step; if (idx >= wrapm) idx = 0;
        }
        float cost_r = (valid && mn > 0) ? s / (2.0f * (float)mn) : INFINITY;
        #pragma unroll
        for (int off = 16; off; off >>= 1)
            cost_r = fminf(cost_r, __shfl_xor(cost_r, off));
        if (r == 0) costs[(size_t)(b * P + g) * P + p] = cost_r;
    } else {
        // ---- reg/sig block for batch b (independent of costs; runs concurrently)
        const int b = blockIdx.x - NCOSTB;
        float regs = 0.0f, sigs = 0.0f;
        const float4* mub = (const float4*)(mu    + (size_t)b * P * D);
        const float4* sgb = (const float4*)(sigma + (size_t)b * P * D);
        for (int i = t; i < P * D / 4; i += 256) {
            const float4 m4 = mub[i];
            regs += m4.x * m4.x + m4.y * m4.y + m4.z * m4.z + m4.w * m4.w;
            const float4 s4 = sgb[i];
            sigs += 1.0f / s4.x + 1.0f / s4.y + 1.0f / s4.z + 1.0f / s4.w;
        }
        #pragma unroll
        for (int off = 32; off; off >>= 1) {
            regs += __shfl_xor(regs, off);
            sigs += __shfl_xor(sigs, off);
        }
        const int w = t >> 6;
        if ((t & 63) == 0) { wred[w] = regs; wred[4 + w] = sigs; }
        __syncthreads();
        if (t == 0) {
            regsum[b] = wred[0] + wred[1] + wred[2] + wred[3];
            sigsum[b] = wred[4] + wred[5] + wred[6] + wred[7];
        }
    }

    // ---- completion: last block of NBLOCKS runs the epilogue
    __syncthreads();
    if (t == 0) {
        __threadfence();
        const unsigned old = atomicAdd(ctr, 1u);
        iflag = (old == (unsigned)(NBLOCKS - 1)) ? 1 : 0;
    }
    __syncthreads();
    if (!iflag) return;
    __threadfence();

    // ---- epilogue: perm / broken / combine, loop over b
    for (int b = 0; b < B; ++b) {
        const float* cb = costs + (size_t)b * P * P;
        for (int i = t; i < P * P; i += 256) sc[i] = cb[i];
        __syncthreads();
        if (t < P) diag[t] = sc[t * P + t];
        if (t == 0) iflag = 0;
        __syncthreads();

        if (t < P) {
            const int g = t; const float dg = diag[g];
            float m = 0.0f;
            for (int p = 0; p < P; ++p) {
                if (p == g) continue;
                m = fmaxf(m, fmaxf(MARGIN - sc[g * P + p] + dg, 0.0f));
            }
            rowmax[g] = m;
        } else if (t < 2 * P) {
            const int p = t - P; const float dp = diag[p];
            float m = 0.0f;
            for (int g = 0; g < P; ++g) {
                if (g == p) continue;
                m = fmaxf(m, fmaxf(MARGIN - sc[g * P + p] + dp, 0.0f));
            }
            colmax[p] = m;
        } else if (t < 3 * P) {
            const int g = t - 2 * P; const float dg = diag[g];
            for (int p = 0; p < P; ++p) {
                if (p == g) continue;
                if (sc[g * P + p] < dg && sc[p * P + g] < diag[p]) { atomicOr(&iflag, 1); break; }
            }
        }
        __syncthreads();

        if (t == 0) {
            const float reg = regsum[b] / (float)P;
            const float sig = sigsum[b] / (float)(P * D);
            float perm = 0.0f;
            for (int i = 0; i < P; ++i) perm += rowmax[i] + colmax[i];
            out[0 * B + b] = L_REG * reg + L_SIGMA * sig + perm;
            out[1 * B + b] = perm;
            out[2 * B + b] = reg;
            out[3 * B + b] = sig;
            out[4 * B + b] = iflag ? 1.0f : 0.0f;
        }
        __syncthreads();  // before next b overwrites sc
    }
}
} // namespace

extern "C" void kernel_launch(void* const* d_in, const int* in_sizes, int n_in,
                              void* d_out, int out_size, void* d_ws, size_t ws_size,
                              hipStream_t stream) {
    const float* gt    = (const float*)d_in[0];
    const float* pred  = (const float*)d_in[1];
    const float* mu    = (const float*)d_in[2];
    const float* sigma = (const float*)d_in[3];
    const int*   mask  = (const int*)d_in[4];
    const int*   cls   = (const int*)d_in[5];
    float* out = (float*)d_out;
    char*  ws  = (char*)d_ws;

    hipMemsetAsync(ws + WS_CTR, 0, sizeof(unsigned), stream);
    fused_kernel<<<NBLOCKS, 256, 0, stream>>>(gt, pred, mu, sigma, mask, cls, out, ws);
}

// Round 3
// 91.801 us; speedup vs baseline: 1.6820x; 1.6820x over previous
//
#include <hip/hip_runtime.h>
#include <math.h>

namespace {
constexpr int B = 4, P = 64, V = 32, D = 256;
constexpr float MARGIN = 0.1f;
constexpr float L_REG = 0.1f, L_SIGMA = 0.05f;

// One wave per (b, g, p-pair): lanes 0-31 -> p0, lanes 32-63 -> p1, r = lane&31.
// Inner loop is global-load-free: gt/pred register-cached, accessed via shuffles.
__global__ __launch_bounds__(256) void costs_kernel(
    const float* __restrict__ gt,    // (B,P,V,2)
    const float* __restrict__ pred,  // (B,P,V,2)
    const int*   __restrict__ mask,  // (B,P,V)
    const int*   __restrict__ cls,   // (B,P)
    float*       __restrict__ costs) // (B,P,P)
{
    const int wid  = blockIdx.x * 4 + (threadIdx.x >> 6);   // [0, 8192)
    const int lane = threadIdx.x & 63;
    const int half = lane >> 5;
    const int r    = lane & 31;
    const int b    = wid >> 11;                  // / (P * P/2)
    const int rem  = wid & 2047;
    const int g    = rem >> 5;
    const int p    = ((rem & 31) << 1) | half;

    // nv via ballot (mask is sorted 0s-then-1s, but count is general anyway)
    const int mg = mask[(b * P + g) * V + r];
    const int mp = mask[(b * P + p) * V + r];
    const unsigned long long bg = __ballot(mg == 0);
    const unsigned long long bp = __ballot(mp == 0);
    const int nvg = __popcll(bg & 0xffffffffULL);            // same in both halves
    const int nvp = half ? __popcll(bp >> 32) : __popcll(bp & 0xffffffffULL);
    const int mn  = (nvg < nvp) ? nvg : nvp;
    const bool is_poly = (cls[b * P + g] == 1);

    // Register cache: lane holds gt[g][r] (replicated across halves) and pred[p_half][r].
    const float2 gv = ((const float2*)(gt   + (size_t)(b * P + g) * (V * 2)))[r];
    const float2 pv = ((const float2*)(pred + (size_t)(b * P + p) * (V * 2)))[r];

    const int psrc_base = half << 5;
    float s = 0.0f;
    #pragma unroll
    for (int v = 0; v < V; ++v) {
        // rotation source index for this lane's rotation r at step v
        int idxp = r + v;                        // poly: (r+v) mod nvg for valid lanes
        idxp = (idxp >= nvg) ? idxp - nvg : idxp;
        const int idxl = (r == 1) ? (V - 1 - v) : v;   // line: fwd / reversed-over-V
        const int idx  = is_poly ? idxp : idxl;  // wave-uniform select

        const float gx = __shfl(gv.x, idx);
        const float gy = __shfl(gv.y, idx);
        const float px = __shfl(pv.x, psrc_base + v);
        const float py = __shfl(pv.y, psrc_base + v);
        if (v < mn) s += fabsf(gx - px) + fabsf(gy - py);
    }

    const bool valid = (mn > 0) && (is_poly ? (r < nvg) : (r < 2));
    float cost_r = valid ? s / (2.0f * (float)mn) : INFINITY;

    // min over the 32 rotations within each half
    #pragma unroll
    for (int off = 16; off; off >>= 1)
        cost_r = fminf(cost_r, __shfl_xor(cost_r, off));
    if (r == 0) costs[(size_t)(b * P + g) * P + p] = cost_r;
}

// One block per batch b.
__global__ __launch_bounds__(256) void finish_kernel(
    const float* __restrict__ costs,  // (B,P,P)
    const float* __restrict__ mu,     // (B,P,D)
    const float* __restrict__ sigma,  // (B,P,D)
    float*       __restrict__ out)    // 5 * B
{
    const int b = blockIdx.x;
    const int t = threadIdx.x;

    __shared__ float sc[P * P];
    __shared__ float diag[P];
    __shared__ float rowmax[P], colmax[P];
    __shared__ float wreg[4], wsig[4];
    __shared__ int broken_s;

    const float* cb = costs + (size_t)b * P * P;
    for (int i = t; i < P * P; i += 256) sc[i] = cb[i];
    __syncthreads();
    if (t < P) diag[t] = sc[t * P + t];
    if (t == 0) broken_s = 0;
    __syncthreads();

    if (t < P) {
        const int g = t;
        const float dg = diag[g];
        float m = 0.0f;
        for (int p = 0; p < P; ++p) {
            if (p == g) continue;
            m = fmaxf(m, fmaxf(MARGIN - sc[g * P + p] + dg, 0.0f));
        }
        rowmax[g] = m;
    } else if (t < 2 * P) {
        const int p = t - P;
        const float dp = diag[p];
        float m = 0.0f;
        for (int g = 0; g < P; ++g) {
            if (g == p) continue;
            m = fmaxf(m, fmaxf(MARGIN - sc[g * P + p] + dp, 0.0f));
        }
        colmax[p] = m;
    } else if (t < 3 * P) {
        const int g = t - 2 * P;
        const float dg = diag[g];
        for (int p = 0; p < P; ++p) {
            if (p == g) continue;
            if (sc[g * P + p] < dg && sc[p * P + g] < diag[p]) { atomicOr(&broken_s, 1); break; }
        }
    }

    float regs = 0.0f, sigs = 0.0f;
    const float4* mub = (const float4*)(mu    + (size_t)b * P * D);
    const float4* sgb = (const float4*)(sigma + (size_t)b * P * D);
    for (int i = t; i < P * D / 4; i += 256) {
        const float4 m4 = mub[i];
        regs += m4.x * m4.x + m4.y * m4.y + m4.z * m4.z + m4.w * m4.w;
        const float4 s4 = sgb[i];
        sigs += 1.0f / s4.x + 1.0f / s4.y + 1.0f / s4.z + 1.0f / s4.w;
    }
    #pragma unroll
    for (int off = 32; off; off >>= 1) {
        regs += __shfl_xor(regs, off);
        sigs += __shfl_xor(sigs, off);
    }
    const int w = t >> 6;
    if ((t & 63) == 0) { wreg[w] = regs; wsig[w] = sigs; }
    __syncthreads();

    if (t == 0) {
        const float reg = (wreg[0] + wreg[1] + wreg[2] + wreg[3]) / (float)P;
        const float sig = (wsig[0] + wsig[1] + wsig[2] + wsig[3]) / (float)(P * D);
        float perm = 0.0f;
        for (int i = 0; i < P; ++i) perm += rowmax[i] + colmax[i];
        out[0 * B + b] = L_REG * reg + L_SIGMA * sig + perm;
        out[1 * B + b] = perm;
        out[2 * B + b] = reg;
        out[3 * B + b] = sig;
        out[4 * B + b] = broken_s ? 1.0f : 0.0f;
    }
}
} // namespace

extern "C" void kernel_launch(void* const* d_in, const int* in_sizes, int n_in,
                              void* d_out, int out_size, void* d_ws, size_t ws_size,
                              hipStream_t stream) {
    const float* gt    = (const float*)d_in[0];
    const float* pred  = (const float*)d_in[1];
    const float* mu    = (const float*)d_in[2];
    const float* sigma = (const float*)d_in[3];
    const int*   mask  = (const int*)d_in[4];
    const int*   cls   = (const int*)d_in[5];
    float* out   = (float*)d_out;
    float* costs = (float*)d_ws;   // B*P*P floats = 64 KiB, fully overwritten

    costs_kernel<<<B * P * (P / 2) / 4, 256, 0, stream>>>(gt, pred, mask, cls, costs);
    finish_kernel<<<B, 256, 0, stream>>>(costs, mu, sigma, out);
}

// Round 4
// 87.226 us; speedup vs baseline: 1.7702x; 1.0525x over previous
//
#include <hip/hip_runtime.h>
#include <math.h>

namespace {
constexpr int B = 4, P = 64, V = 32, D = 256;
constexpr float MARGIN = 0.1f;
constexpr float L_REG = 0.1f, L_SIGMA = 0.05f;

// One wave per (b, g, p-pair): lanes 0-31 -> p0, lanes 32-63 -> p1, r = lane&31.
// gt comes from register cache via 2 shuffles/step; pred via half-uniform
// global_load_dwordx2 (broadcast, L1-hit, VMEM pipe). Dynamic wave-uniform
// trip count loopN = max over halves of mn (~18 avg vs 32).
__global__ __launch_bounds__(256) void costs_kernel(
    const float* __restrict__ gt,    // (B,P,V,2)
    const float* __restrict__ pred,  // (B,P,V,2)
    const int*   __restrict__ mask,  // (B,P,V)
    const int*   __restrict__ cls,   // (B,P)
    float*       __restrict__ costs) // (B,P,P)
{
    const int wid  = blockIdx.x * 4 + (threadIdx.x >> 6);   // [0, 8192)
    const int lane = threadIdx.x & 63;
    const int r    = lane & 31;
    const int half = lane >> 5;
    const int b    = wid >> 11;                  // / (P * P/2)
    const int rem  = wid & 2047;
    const int g    = rem >> 5;
    const int p    = ((rem & 31) << 1) | half;

    const int mg = mask[(b * P + g) * V + r];
    const int mp = mask[(b * P + p) * V + r];
    const unsigned long long bg = __ballot(mg == 0);
    const unsigned long long bp = __ballot(mp == 0);
    const int nvg = __popcll(bg & 0xffffffffULL);            // wave-uniform
    const int nvp = half ? __popcll(bp >> 32) : __popcll(bp & 0xffffffffULL);
    const int mn  = (nvg < nvp) ? nvg : nvp;                 // per-half uniform
    const bool is_poly = (cls[b * P + g] == 1);              // wave-uniform

    // Register cache of gt row (replicated in both halves): lane L holds gt[g][L&31]
    const float2 gv = ((const float2*)(gt + (size_t)(b * P + g) * (V * 2)))[r];
    const float2* prp2 = (const float2*)(pred + (size_t)(b * P + p) * (V * 2));

    const int mn_other = __shfl_xor(mn, 32);
    const int loopN = (mn > mn_other) ? mn : mn_other;       // wave-uniform

    float s = 0.0f;
    for (int v = 0; v < loopN; ++v) {
        int idxp = r + v;                                    // (r+v) mod nvg, valid lanes
        idxp -= (idxp >= nvg) ? nvg : 0;
        const int idxl = (r == 1) ? (V - 1 - v) : v;
        const int idx  = is_poly ? idxp : idxl;
        const float gx = __shfl(gv.x, idx);
        const float gy = __shfl(gv.y, idx);
        const float2 pvv = prp2[v];                          // half-uniform broadcast load
        if (v < mn) s += fabsf(gx - pvv.x) + fabsf(gy - pvv.y);
    }

    const bool valid = (mn > 0) && (is_poly ? (r < nvg) : (r < 2));
    float cost_r = valid ? s / (2.0f * (float)mn) : INFINITY;

    #pragma unroll
    for (int off = 16; off; off >>= 1)
        cost_r = fminf(cost_r, __shfl_xor(cost_r, off));
    if (r == 0) costs[(size_t)(b * P + g) * P + p] = cost_r;
}

// One block per batch b.
__global__ __launch_bounds__(256) void finish_kernel(
    const float* __restrict__ costs,  // (B,P,P)
    const float* __restrict__ mu,     // (B,P,D)
    const float* __restrict__ sigma,  // (B,P,D)
    float*       __restrict__ out)    // 5 * B
{
    const int b = blockIdx.x;
    const int t = threadIdx.x;

    __shared__ float sc[P * P];
    __shared__ float diag[P];
    __shared__ float rowmax[P], colmax[P];
    __shared__ float wreg[4], wsig[4];
    __shared__ int broken_s;

    const float* cb = costs + (size_t)b * P * P;
    for (int i = t; i < P * P; i += 256) sc[i] = cb[i];
    __syncthreads();
    if (t < P) diag[t] = sc[t * P + t];
    if (t == 0) broken_s = 0;
    __syncthreads();

    if (t < P) {
        const int g = t;
        const float dg = diag[g];
        float m = 0.0f;
        for (int p = 0; p < P; ++p) {
            if (p == g) continue;
            m = fmaxf(m, fmaxf(MARGIN - sc[g * P + p] + dg, 0.0f));
        }
        rowmax[g] = m;
    } else if (t < 2 * P) {
        const int p = t - P;
        const float dp = diag[p];
        float m = 0.0f;
        for (int g = 0; g < P; ++g) {
            if (g == p) continue;
            m = fmaxf(m, fmaxf(MARGIN - sc[g * P + p] + dp, 0.0f));
        }
        colmax[p] = m;
    } else if (t < 3 * P) {
        const int g = t - 2 * P;
        const float dg = diag[g];
        for (int p = 0; p < P; ++p) {
            if (p == g) continue;
            if (sc[g * P + p] < dg && sc[p * P + g] < diag[p]) { atomicOr(&broken_s, 1); break; }
        }
    }

    float regs = 0.0f, sigs = 0.0f;
    const float4* mub = (const float4*)(mu    + (size_t)b * P * D);
    const float4* sgb = (const float4*)(sigma + (size_t)b * P * D);
    for (int i = t; i < P * D / 4; i += 256) {
        const float4 m4 = mub[i];
        regs += m4.x * m4.x + m4.y * m4.y + m4.z * m4.z + m4.w * m4.w;
        const float4 s4 = sgb[i];
        sigs += 1.0f / s4.x + 1.0f / s4.y + 1.0f / s4.z + 1.0f / s4.w;
    }
    #pragma unroll
    for (int off = 32; off; off >>= 1) {
        regs += __shfl_xor(regs, off);
        sigs += __shfl_xor(sigs, off);
    }
    const int w = t >> 6;
    if ((t & 63) == 0) { wreg[w] = regs; wsig[w] = sigs; }
    __syncthreads();

    if (t == 0) {
        const float reg = (wreg[0] + wreg[1] + wreg[2] + wreg[3]) / (float)P;
        const float sig = (wsig[0] + wsig[1] + wsig[2] + wsig[3]) / (float)(P * D);
        float perm = 0.0f;
        for (int i = 0; i < P; ++i) perm += rowmax[i] + colmax[i];
        out[0 * B + b] = L_REG * reg + L_SIGMA * sig + perm;
        out[1 * B + b] = perm;
        out[2 * B + b] = reg;
        out[3 * B + b] = sig;
        out[4 * B + b] = broken_s ? 1.0f : 0.0f;
    }
}
} // namespace

extern "C" void kernel_launch(void* const* d_in, const int* in_sizes, int n_in,
                              void* d_out, int out_size, void* d_ws, size_t ws_size,
                              hipStream_t stream) {
    const float* gt    = (const float*)d_in[0];
    const float* pred  = (const float*)d_in[1];
    const float* mu    = (const float*)d_in[2];
    const float* sigma = (const float*)d_in[3];
    const int*   mask  = (const int*)d_in[4];
    const int*   cls   = (const int*)d_in[5];
    float* out   = (float*)d_out;
    float* costs = (float*)d_ws;   // B*P*P floats = 64 KiB, fully overwritten

    costs_kernel<<<B * P * (P / 2) / 4, 256, 0, stream>>>(gt, pred, mask, cls, costs);
    finish_kernel<<<B, 256, 0, stream>>>(costs, mu, sigma, out);
}